// Round 7
// baseline (46.300 us; speedup 1.0000x reference)
//
#include <hip/hip_runtime.h>
#include <math.h>

#define T1 17
#define NN 2048
#define DIN 9
#define CC 8
#define KK 5
#define NSTR 5                 // donor streams per thread (512-thr block)
#define NDCAP (NSTR * 256)     // 1280 donor slots (E[ndon]=1024, +11 sigma)
#define NQCAP 1280             // query slots (nq = 2048 - ndon <= 1280)
#define LPAD (NDCAP + 8)
#define NU (NDCAP / 64)        // 20 cached distances per lane
#define PLANE (NN * CC)

#define XD_BYTES (T1 * NN * CC * 4)

// ---------------------------------------------------------------------------
// prep_a (16 blocks x 128): per-row bitmask, donor ballot per 64-row group,
// passthrough output writes, per-group colmean partial sums.
__global__ __launch_bounds__(128) void prep_a(
    const float* __restrict__ x_all, const int* __restrict__ mask,
    unsigned* __restrict__ pm, unsigned long long* __restrict__ wsbal,
    float* __restrict__ wscol, float* __restrict__ out) {
  const int row = blockIdx.x * 128 + threadIdx.x;
  const int lane = threadIdx.x & 63;
  const int g = row >> 6;  // global 64-row group id [0,32)
  unsigned m = 0;
#pragma unroll
  for (int t = 0; t < T1; ++t)
    m |= (mask[t * NN + row] == 0 ? 1u : 0u) << t;
  pm[row] = m;
  const bool v = (m >> 16) & 1u;
  const unsigned long long bal = __ballot(v);

  float s[CC];
#pragma unroll
  for (int c = 0; c < CC; ++c) s[c] = 0.f;
  if (v) {
    const float* r = x_all + ((size_t)16 * NN + row) * DIN;
#pragma unroll
    for (int c = 0; c < CC; ++c) {
      const float vv = r[c];
      s[c] = vv;
      out[row * CC + c] = vv;
    }
  }
#pragma unroll
  for (int off = 32; off > 0; off >>= 1) {
#pragma unroll
    for (int c = 0; c < CC; ++c) s[c] += __shfl_down(s[c], off);
  }
  if (lane == 0) {
    wsbal[g] = bal;
#pragma unroll
    for (int c = 0; c < CC; ++c) wscol[g * CC + c] = s[c];
  }
}

// ---------------------------------------------------------------------------
// prep_b (1 block x 1024): prefix over 32 group counts, ordered scatter of
// donors/queries, colmean finalize.
__global__ __launch_bounds__(1024) void prep_b(
    const unsigned* __restrict__ pm, const unsigned long long* __restrict__ wsbal,
    const float* __restrict__ wscol, int* __restrict__ dlist,
    unsigned* __restrict__ pmd, int* __restrict__ qlist,
    float* __restrict__ colmean, int* __restrict__ cnts) {
  __shared__ int dpre[33], qpre[33];
  __shared__ unsigned long long sbal[32];
  const int tid = threadIdx.x;
  if (tid < 32) sbal[tid] = wsbal[tid];
  __syncthreads();
  if (tid == 0) {
    int a = 0, b = 0;
    for (int g = 0; g < 32; ++g) {
      dpre[g] = a;
      qpre[g] = b;
      const int p = (int)__popcll(sbal[g]);
      a += p;
      b += 64 - p;
    }
    dpre[32] = a;
    qpre[32] = b;
    cnts[0] = a;  // ndon
    cnts[1] = b;  // nq
  }
  __syncthreads();
#pragma unroll
  for (int h = 0; h < 2; ++h) {
    const int row = tid + h * 1024;
    const unsigned m = pm[row];
    const int g = row >> 6, l = row & 63;
    const unsigned long long bal = sbal[g];
    const unsigned long long ltm = (1ull << l) - 1ull;  // lane 0 -> 0
    if ((m >> 16) & 1u) {
      const int p = dpre[g] + (int)__popcll(bal & ltm);
      dlist[p] = row;
      pmd[p] = m;
    } else {
      const int p = qpre[g] + (int)__popcll((~bal) & ltm);
      qlist[p] = row;
    }
  }
  if (tid < CC) {
    float tot = 0.f;
#pragma unroll
    for (int g = 0; g < 32; ++g) tot += wscol[g * CC + tid];
    colmean[tid] = tot / fmaxf((float)dpre[32], 1.f);
  }
}

// ---------------------------------------------------------------------------
// Pack donor data: xd[t][dn][c] = x_all[t][dlist[dn]][c]
__global__ void transpose_kernel(const float* __restrict__ x_all,
                                 const int* __restrict__ dlist,
                                 const int* __restrict__ cnts,
                                 float* __restrict__ xd) {
  const int u = blockIdx.x * 256 + threadIdx.x;
  if (u >= T1 * NN * CC) return;
  const int t = u / (NN * CC);
  const int rem = u % (NN * CC);
  const int dn = rem >> 3;
  const int c = rem & 7;
  if (dn < cnts[0]) xd[u] = x_all[((size_t)t * NN + dlist[dn]) * DIN + c];
}

// ---------------------------------------------------------------------------
// Main: one block (512 thr) per QUERY row (compacted). Scalar (SGPR) t-walk
// over mi's set bits, two bits per iteration (odd tail padded with t=16 whose
// flag is provably 0); per-stream element offsets precomputed once -> loads
// are saddr+voffset with no per-iter address VALU; exec-mask guard skips dead
// donors' loads entirely. Selection: wave w = channel w, register-cached 20
// values, 5 extraction rounds (bit-exact, lowest-index ties == numpy top_k).
__global__ __launch_bounds__(512, 3) void knn_main(
    const float* __restrict__ x_all, const float* __restrict__ xd,
    const unsigned* __restrict__ pm, const unsigned* __restrict__ pmd,
    const int* __restrict__ qlist, const int* __restrict__ cnts,
    const float* __restrict__ colmean, float* __restrict__ out) {
  __shared__ float sdist[CC][LPAD];  // 41,216 B
  __shared__ float qlds[T1][CC];     // row 16 = zeros (pad; flag always 0)
  __shared__ float rcp17[32];
  const int nq = cnts[1];
  const int bid = blockIdx.x;
  if (bid >= nq) return;
  const int i = qlist[bid];          // missing at t=16 by construction
  const int ndon = cnts[0];
  const unsigned mi = (unsigned)__builtin_amdgcn_readfirstlane((int)pm[i]);  // SGPR
  const int tid = threadIdx.x;

  if (tid < 32) rcp17[tid] = 17.f / (float)tid;  // [0] = inf, guarded
  if (tid < 16 * CC)
    qlds[tid >> 3][tid & 7] = x_all[((size_t)(tid >> 3) * NN + i) * DIN + (tid & 7)];
  if (tid >= 16 * CC && tid < 17 * CC) qlds[16][tid & 7] = 0.f;
  __syncthreads();

  const int qd = tid & 1;       // channel half -> c0..c0+3
  const int c0 = qd * 4;
  const int dg = tid >> 1;      // [0,256)
  const int lane = tid & 63;
  const int w = tid >> 6;       // wave id = channel

  // ---- distance phase ----
  float a0[NSTR], a1[NSTR], a2[NSTR], a3[NSTR];
  unsigned ms[NSTR];
  int eoff[NSTR];               // element offset within a t-plane (per-lane)
#pragma unroll
  for (int s = 0; s < NSTR; ++s) {
    const int dn = dg + 256 * s;
    ms[s] = (dn < ndon) ? (mi & pmd[dn]) : 0u;
    eoff[s] = dn * CC + c0;
    a0[s] = a1[s] = a2[s] = a3[s] = 0.f;
  }

  unsigned tm = mi & 0xFFFFu;   // SGPR walk (mi is scalar)
  while (tm) {
    const int t0 = __ffs(tm) - 1;
    tm &= tm - 1u;
    int t1 = 16;                 // pad: flag at t=16 is provably 0
    if (tm) { t1 = __ffs(tm) - 1; tm &= tm - 1u; }
    const float* __restrict__ p0 = xd + (size_t)t0 * PLANE;  // SGPR base
    const float* __restrict__ p1 = xd + (size_t)t1 * PLANE;  // SGPR base
    const float4 qv0 = *(const float4*)&qlds[t0][c0];
    const float4 qv1 = *(const float4*)&qlds[t1][c0];
#pragma unroll
    for (int s = 0; s < NSTR; ++s) {
      if (ms[s]) {  // exec-masked: dead lanes issue no loads
        const float4 dv0 = *(const float4*)(p0 + eoff[s]);
        const float4 dv1 = *(const float4*)(p1 + eoff[s]);
        const float fl0 = (float)((ms[s] >> t0) & 1u);
        const float fl1 = (float)((ms[s] >> t1) & 1u);
        float e;
        e = qv0.x - dv0.x; a0[s] = fmaf(e * e, fl0, a0[s]);
        e = qv0.y - dv0.y; a1[s] = fmaf(e * e, fl0, a1[s]);
        e = qv0.z - dv0.z; a2[s] = fmaf(e * e, fl0, a2[s]);
        e = qv0.w - dv0.w; a3[s] = fmaf(e * e, fl0, a3[s]);
        e = qv1.x - dv1.x; a0[s] = fmaf(e * e, fl1, a0[s]);
        e = qv1.y - dv1.y; a1[s] = fmaf(e * e, fl1, a1[s]);
        e = qv1.z - dv1.z; a2[s] = fmaf(e * e, fl1, a2[s]);
        e = qv1.w - dv1.w; a3[s] = fmaf(e * e, fl1, a3[s]);
      }
    }
  }

#pragma unroll
  for (int s = 0; s < NSTR; ++s) {
    const int dn = dg + 256 * s;
    const int cnt = __popc(ms[s]);
    const float sc = rcp17[cnt & 31];
    const bool ok = cnt > 0;
    sdist[c0 + 0][dn] = ok ? sqrtf(a0[s] * sc) : INFINITY;
    sdist[c0 + 1][dn] = ok ? sqrtf(a1[s] * sc) : INFINITY;
    sdist[c0 + 2][dn] = ok ? sqrtf(a2[s] * sc) : INFINITY;
    sdist[c0 + 3][dn] = ok ? sqrtf(a3[s] * sc) : INFINITY;
  }
  __syncthreads();

  // ---- selection: wave w handles channel w ----
  float dvr[NU];
#pragma unroll
  for (int u = 0; u < NU; ++u) dvr[u] = sdist[w][u * 64 + lane];

  float sum = 0.f;
  int cn = 0;
#pragma unroll
  for (int k = 0; k < KK; ++k) {
    float g = dvr[0];
#pragma unroll
    for (int u = 1; u < NU; ++u) g = fminf(g, dvr[u]);
#pragma unroll
    for (int off = 32; off > 0; off >>= 1) g = fminf(g, __shfl_xor(g, off));
    if (g < INFINITY) {  // wave-uniform
      int jloc = 0x7FFFFFFF;
#pragma unroll
      for (int u = NU - 1; u >= 0; --u)
        if (dvr[u] == g) jloc = u * 64 + lane;  // lowest u => lowest index
      int jg = jloc;
#pragma unroll
      for (int off = 32; off > 0; off >>= 1) jg = min(jg, __shfl_xor(jg, off));
      const int jgs = __builtin_amdgcn_readfirstlane(jg);
      const int tu = jgs >> 6, tl = jgs & 63;
#pragma unroll
      for (int u = 0; u < NU; ++u)
        if (u == tu) dvr[u] = (lane == tl) ? INFINITY : dvr[u];
      sum += xd[((size_t)16 * NN + jgs) * CC + w];  // ascending (d,j) order
      ++cn;
    }
  }
  if (lane == 0) out[i * CC + w] = (cn > 0) ? sum / (float)cn : colmean[w];
}

// ---------------------------------------------------------------------------
extern "C" void kernel_launch(void* const* d_in, const int* in_sizes, int n_in,
                              void* d_out, int out_size, void* d_ws, size_t ws_size,
                              hipStream_t stream) {
  const float* x_all = (const float*)d_in[0];  // [17, 2048, 9] f32
  const int* mask = (const int*)d_in[1];       // [17, 2048] i32
  float* out = (float*)d_out;                  // [2048, 8] f32

  char* ws = (char*)d_ws;
  float* xd = (float*)ws;
  unsigned* pm = (unsigned*)(ws + XD_BYTES);
  int* dlist = (int*)(ws + XD_BYTES + NN * 4);
  unsigned* pmd = (unsigned*)(ws + XD_BYTES + NN * 8);
  int* qlist = (int*)(ws + XD_BYTES + NN * 12);
  float* colmean = (float*)(ws + XD_BYTES + NN * 16);
  int* cnts = (int*)(ws + XD_BYTES + NN * 16 + CC * 4);
  unsigned long long* wsbal = (unsigned long long*)(ws + XD_BYTES + NN * 16 + CC * 4 + 64);
  float* wscol = (float*)(ws + XD_BYTES + NN * 16 + CC * 4 + 64 + 32 * 8);

  prep_a<<<16, 128, 0, stream>>>(x_all, mask, pm, wsbal, wscol, out);
  prep_b<<<1, 1024, 0, stream>>>(pm, wsbal, wscol, dlist, pmd, qlist, colmean, cnts);
  transpose_kernel<<<(T1 * NN * CC + 255) / 256, 256, 0, stream>>>(x_all, dlist, cnts, xd);
  knn_main<<<NQCAP, 512, 0, stream>>>(x_all, xd, pm, pmd, qlist, cnts, colmean, out);
}